// Round 1
// baseline (555.597 us; speedup 1.0000x reference)
//
#include <hip/hip_runtime.h>

#define NROWS   262144
#define INF     64
#define HIDN    256
#define NOUTM   60

// ---------------------------------------------------------------------------
// 4x4 symmetric eigensolver via fully-unrolled cyclic Jacobi.
// Returns eigenvector of the LARGEST eigenvalue, sign-normalized so q[0]>=0
// (sign(0) -> +1, matching the jnp reference).
// All indices compile-time constant -> stays in registers (no scratch).
// ---------------------------------------------------------------------------
__device__ __forceinline__ void jacobi_quat(const float* zv, float* qout) {
  float M[4][4];
  M[0][0] = zv[0]; M[0][1] = zv[1]; M[0][2] = zv[2]; M[0][3] = zv[3];
  M[1][1] = zv[4]; M[1][2] = zv[5]; M[1][3] = zv[6];
  M[2][2] = zv[7]; M[2][3] = zv[8]; M[3][3] = zv[9];
  M[1][0] = zv[1]; M[2][0] = zv[2]; M[3][0] = zv[3];
  M[2][1] = zv[5]; M[3][1] = zv[6]; M[3][2] = zv[8];
  float V[4][4] = {{1.f,0.f,0.f,0.f},{0.f,1.f,0.f,0.f},
                   {0.f,0.f,1.f,0.f},{0.f,0.f,0.f,1.f}};

#define JROT(p, q) do {                                                      \
    float apq = M[p][q];                                                     \
    if (fabsf(apq) > 1e-25f) {                                               \
      float app = M[p][p], aqq = M[q][q];                                    \
      float tau = (aqq - app) * (0.5f / apq);                                \
      float t   = copysignf(1.0f, tau) /                                     \
                  (fabsf(tau) + sqrtf(1.0f + tau * tau));                    \
      float c   = rsqrtf(1.0f + t * t);                                      \
      float s   = t * c;                                                     \
      M[p][p] = app - t * apq;                                               \
      M[q][q] = aqq + t * apq;                                               \
      M[p][q] = 0.0f; M[q][p] = 0.0f;                                        \
      _Pragma("unroll")                                                      \
      for (int r = 0; r < 4; ++r) {                                          \
        if (r != p && r != q) {                                              \
          float arp = M[r][p], arq = M[r][q];                                \
          float nrp = c * arp - s * arq;                                     \
          float nrq = s * arp + c * arq;                                     \
          M[r][p] = nrp; M[p][r] = nrp;                                      \
          M[r][q] = nrq; M[q][r] = nrq;                                      \
        }                                                                    \
      }                                                                      \
      _Pragma("unroll")                                                      \
      for (int r = 0; r < 4; ++r) {                                          \
        float vrp = V[r][p], vrq = V[r][q];                                  \
        V[r][p] = c * vrp - s * vrq;                                         \
        V[r][q] = s * vrp + c * vrq;                                         \
      }                                                                      \
    }                                                                        \
  } while (0)

  #pragma unroll
  for (int sweep = 0; sweep < 8; ++sweep) {
    JROT(0, 1); JROT(0, 2); JROT(0, 3);
    JROT(1, 2); JROT(1, 3); JROT(2, 3);
  }
#undef JROT

  // argmax over diagonal, select column of V (cndmask chain, no runtime idx)
  float bv = M[0][0];
  float q0 = V[0][0], q1 = V[1][0], q2 = V[2][0], q3 = V[3][0];
  #pragma unroll
  for (int j = 1; j < 4; ++j) {
    float dj = M[j][j];
    bool  b  = dj > bv;
    bv = b ? dj      : bv;
    q0 = b ? V[0][j] : q0;
    q1 = b ? V[1][j] : q1;
    q2 = b ? V[2][j] : q2;
    q3 = b ? V[3][j] : q3;
  }
  float sgn = (q0 < 0.0f) ? -1.0f : 1.0f;  // sign(0) -> +1
  qout[0] = q0 * sgn; qout[1] = q1 * sgn;
  qout[2] = q2 * sgn; qout[3] = q3 * sgn;
}

// ---------------------------------------------------------------------------
// fp32 baseline: one thread per row. Weight loads are wave-uniform -> scalar
// loads through K$; z/h/acc in VGPRs. Hidden dim processed in chunks of 16 to
// bound register pressure (zv 64 + acc 60 + h 16 ~ 150 VGPR).
// ---------------------------------------------------------------------------
__global__ __launch_bounds__(256)
void veronese_fused_f32(const float* __restrict__ z,
                        const float* __restrict__ W1,
                        const float* __restrict__ b1,
                        const float* __restrict__ W2,
                        const float* __restrict__ b2,
                        float* __restrict__ out) {
  int row = blockIdx.x * 256 + threadIdx.x;
  if (row >= NROWS) return;

  const float* zr = z + (size_t)row * INF;
  float zv[INF];
  #pragma unroll
  for (int i = 0; i < INF / 4; ++i) {
    float4 v = reinterpret_cast<const float4*>(zr)[i];
    zv[4*i+0] = v.x; zv[4*i+1] = v.y; zv[4*i+2] = v.z; zv[4*i+3] = v.w;
  }

  float q[4];
  jacobi_quat(zv, q);

  float acc[NOUTM];
  #pragma unroll
  for (int n = 0; n < NOUTM; ++n) acc[n] = b2[n];

  for (int c = 0; c < HIDN; c += 16) {   // runtime loop keeps I$ bounded
    float h[16];
    #pragma unroll
    for (int j = 0; j < 16; ++j) h[j] = b1[c + j];
    #pragma unroll
    for (int k = 0; k < INF; ++k) {
      float zk = zv[k];
      #pragma unroll
      for (int j = 0; j < 16; ++j)
        h[j] = fmaf(zk, W1[k * HIDN + c + j], h[j]);
    }
    #pragma unroll
    for (int j = 0; j < 16; ++j) h[j] = fmaxf(h[j], 0.0f);
    #pragma unroll
    for (int j = 0; j < 16; ++j) {
      float hj = h[j];
      #pragma unroll
      for (int n = 0; n < NOUTM; ++n)
        acc[n] = fmaf(hj, W2[(c + j) * NOUTM + n], acc[n]);
    }
  }

  float* op = out + (size_t)row * 64;
  float4 o0 = make_float4(q[0], q[1], q[2], q[3]);
  reinterpret_cast<float4*>(op)[0] = o0;
  #pragma unroll
  for (int i = 0; i < 15; ++i) {
    float4 v = make_float4(acc[4*i+0], acc[4*i+1], acc[4*i+2], acc[4*i+3]);
    reinterpret_cast<float4*>(op)[i + 1] = v;
  }
}

extern "C" void kernel_launch(void* const* d_in, const int* in_sizes, int n_in,
                              void* d_out, int out_size, void* d_ws, size_t ws_size,
                              hipStream_t stream) {
  const float* z  = (const float*)d_in[0];
  const float* W1 = (const float*)d_in[1];
  const float* b1 = (const float*)d_in[2];
  const float* W2 = (const float*)d_in[3];
  const float* b2 = (const float*)d_in[4];
  float* out = (float*)d_out;

  dim3 grid(NROWS / 256), block(256);
  hipLaunchKernelGGL(veronese_fused_f32, grid, block, 0, stream,
                     z, W1, b1, W2, b2, out);
}

// Round 3
// 315.833 us; speedup vs baseline: 1.7591x; 1.7591x over previous
//
#include <hip/hip_runtime.h>
#include <stdint.h>

#define NROWS 262144
#define INF   64
#define HIDN  256
#define OUTM  60

#define ROWS_PER_BLK_ITER 128      // 4 waves x 32 rows
#define MLP_BLOCKS 512
#define MLP_ITERS  (NROWS / (ROWS_PER_BLK_ITER * MLP_BLOCKS))  // 4

typedef __attribute__((ext_vector_type(8))) short bf16x8;
typedef __attribute__((ext_vector_type(4))) float f32x4;

__device__ __forceinline__ uint16_t f2bf(float f) {
  uint32_t x = __builtin_bit_cast(uint32_t, f);
  x += 0x7fffu + ((x >> 16) & 1u);          // RNE
  return (uint16_t)(x >> 16);
}
__device__ __forceinline__ uint32_t pk2(float lo, float hi) {
  return (uint32_t)f2bf(lo) | ((uint32_t)f2bf(hi) << 16);
}

union U8 { uint32_t u[4]; bf16x8 v; uint4 q; };

// ---------------------------------------------------------------------------
// K1: quaternion via fully-unrolled cyclic Jacobi (8 sweeps), 1 thread/row.
// Verified in round 1 (absmax 0.0039 fp32).
// ---------------------------------------------------------------------------
__global__ __launch_bounds__(256)
void veronese_quat(const float* __restrict__ z, float* __restrict__ out) {
  int row = blockIdx.x * 256 + threadIdx.x;
  const float* zr = z + (size_t)row * INF;
  float4 v0 = reinterpret_cast<const float4*>(zr)[0];
  float4 v1 = reinterpret_cast<const float4*>(zr)[1];
  float4 v2 = reinterpret_cast<const float4*>(zr)[2];
  float zv[10] = {v0.x,v0.y,v0.z,v0.w, v1.x,v1.y,v1.z,v1.w, v2.x,v2.y};

  float M[4][4];
  M[0][0]=zv[0]; M[0][1]=zv[1]; M[0][2]=zv[2]; M[0][3]=zv[3];
  M[1][1]=zv[4]; M[1][2]=zv[5]; M[1][3]=zv[6];
  M[2][2]=zv[7]; M[2][3]=zv[8]; M[3][3]=zv[9];
  M[1][0]=zv[1]; M[2][0]=zv[2]; M[3][0]=zv[3];
  M[2][1]=zv[5]; M[3][1]=zv[6]; M[3][2]=zv[8];
  float V[4][4] = {{1.f,0.f,0.f,0.f},{0.f,1.f,0.f,0.f},
                   {0.f,0.f,1.f,0.f},{0.f,0.f,0.f,1.f}};

#define JROT(p, q) do {                                                      \
    float apq = M[p][q];                                                     \
    if (fabsf(apq) > 1e-25f) {                                               \
      float app = M[p][p], aqq = M[q][q];                                    \
      float tau = (aqq - app) * (0.5f / apq);                                \
      float t   = copysignf(1.0f, tau) /                                     \
                  (fabsf(tau) + sqrtf(1.0f + tau * tau));                    \
      float c   = rsqrtf(1.0f + t * t);                                      \
      float s   = t * c;                                                     \
      M[p][p] = app - t * apq;                                               \
      M[q][q] = aqq + t * apq;                                               \
      M[p][q] = 0.0f; M[q][p] = 0.0f;                                        \
      _Pragma("unroll")                                                      \
      for (int r = 0; r < 4; ++r) {                                          \
        if (r != p && r != q) {                                              \
          float arp = M[r][p], arq = M[r][q];                                \
          float nrp = c * arp - s * arq;                                     \
          float nrq = s * arp + c * arq;                                     \
          M[r][p] = nrp; M[p][r] = nrp;                                      \
          M[r][q] = nrq; M[q][r] = nrq;                                      \
        }                                                                    \
      }                                                                      \
      _Pragma("unroll")                                                      \
      for (int r = 0; r < 4; ++r) {                                          \
        float vrp = V[r][p], vrq = V[r][q];                                  \
        V[r][p] = c * vrp - s * vrq;                                         \
        V[r][q] = s * vrp + c * vrq;                                         \
      }                                                                      \
    }                                                                        \
  } while (0)

  #pragma unroll
  for (int sweep = 0; sweep < 8; ++sweep) {
    JROT(0, 1); JROT(0, 2); JROT(0, 3);
    JROT(1, 2); JROT(1, 3); JROT(2, 3);
  }
#undef JROT

  float bv = M[0][0];
  float q0 = V[0][0], q1 = V[1][0], q2 = V[2][0], q3 = V[3][0];
  #pragma unroll
  for (int j = 1; j < 4; ++j) {
    float dj = M[j][j];
    bool  b  = dj > bv;
    bv = b ? dj      : bv;
    q0 = b ? V[0][j] : q0;
    q1 = b ? V[1][j] : q1;
    q2 = b ? V[2][j] : q2;
    q3 = b ? V[3][j] : q3;
  }
  float sgn = (q0 < 0.0f) ? -1.0f : 1.0f;  // sign(0) -> +1
  float4 q = make_float4(q0*sgn, q1*sgn, q2*sgn, q3*sgn);
  *reinterpret_cast<float4*>(out + (size_t)row * 64) = q;
}

// ---------------------------------------------------------------------------
// K2: fused 2-layer MLP with bf16 MFMA (transposed formulation).
//  H^T[256x16] = W1T[256x64] @ Z^T[64x16];  O^T[64x16] = W2T[64x256] @ H^T
//  LDS: W1T [256][64] bf16 @0 (rows 128B), W2T [64][256] bf16 @32768 (rows
//  512B), both XOR-swizzled with ((row&7)<<4) on 16B units.
//  Layer1->layer2 handoff: each consumer word p comes from source lane
//  l15 + 16*((2g+(p>>1))&3), word index 2*(CONSUMER g>>1) + (p&1). Since
//  __shfl evaluates var on the SOURCE lane, fetch BOTH candidate words and
//  cndmask on (g&2).  [round-2 bug: selected by source's l -> permuted H]
// ---------------------------------------------------------------------------
__global__ __launch_bounds__(256, 2)
void veronese_mlp(const float* __restrict__ z,  const float* __restrict__ W1,
                  const float* __restrict__ b1, const float* __restrict__ W2,
                  const float* __restrict__ b2, float* __restrict__ out) {
  __shared__ __align__(16) uint8_t lds[65536];
  const int tid = threadIdx.x;

  // ---- stage W1T: thread t owns hid row t ----
  {
    const int hid = tid;
    #pragma unroll
    for (int hc = 0; hc < 8; ++hc) {
      float f[8];
      #pragma unroll
      for (int j = 0; j < 8; ++j) f[j] = W1[(hc*8 + j) * HIDN + hid];
      U8 u;
      u.u[0] = pk2(f[0], f[1]); u.u[1] = pk2(f[2], f[3]);
      u.u[2] = pk2(f[4], f[5]); u.u[3] = pk2(f[6], f[7]);
      uint32_t off = (uint32_t)hid * 128 + (uint32_t)((hc * 16) ^ ((hid & 7) << 4));
      *reinterpret_cast<uint4*>(lds + off) = u.q;
    }
  }
  // ---- stage W2T: thread t owns out row t&63, hid quarter t>>6 ----
  {
    const int o  = tid & 63;
    const int qq = tid >> 6;
    #pragma unroll
    for (int hc = 0; hc < 8; ++hc) {
      const int hb = qq * 64 + hc * 8;
      float f[8];
      #pragma unroll
      for (int j = 0; j < 8; ++j)
        f[j] = (o < OUTM) ? W2[(hb + j) * OUTM + o] : 0.0f;
      U8 u;
      u.u[0] = pk2(f[0], f[1]); u.u[1] = pk2(f[2], f[3]);
      u.u[2] = pk2(f[4], f[5]); u.u[3] = pk2(f[6], f[7]);
      uint32_t off = 32768u + (uint32_t)o * 512 + (uint32_t)((hb * 2) ^ ((o & 7) << 4));
      *reinterpret_cast<uint4*>(lds + off) = u.q;
    }
  }
  __syncthreads();

  const int l   = tid & 63;
  const int w   = tid >> 6;
  const int g   = l >> 4;
  const int l15 = l & 15;
  const uint32_t swz = (uint32_t)((l & 7) << 4);

  // bias2 preload: out = 16*m + 4*g (+r)
  f32x4 bias2[4];
  #pragma unroll
  for (int m = 0; m < 4; ++m) {
    int ob = 16*m + 4*g;
    if (ob < OUTM) bias2[m] = *reinterpret_cast<const f32x4*>(b2 + ob);
    else           bias2[m] = (f32x4){0.f, 0.f, 0.f, 0.f};
  }

  for (int it = 0; it < MLP_ITERS; ++it) {
    const int rowBase = (blockIdx.x * MLP_ITERS + it) * ROWS_PER_BLK_ITER;
    const int r0 = rowBase + w * 32 + l15;
    const int r1 = r0 + 16;
    const float* zp0 = z + (size_t)r0 * INF;
    const float* zp1 = z + (size_t)r1 * INF;

    // Z^T B-fragments: lane holds Z[row=l15 (+16)][in=32k1+8g+j]
    bf16x8 zf[2][2];
    #pragma unroll
    for (int k1 = 0; k1 < 2; ++k1) {
      float4 a0 = *reinterpret_cast<const float4*>(zp0 + k1*32 + 8*g);
      float4 a1 = *reinterpret_cast<const float4*>(zp0 + k1*32 + 8*g + 4);
      float4 c0 = *reinterpret_cast<const float4*>(zp1 + k1*32 + 8*g);
      float4 c1 = *reinterpret_cast<const float4*>(zp1 + k1*32 + 8*g + 4);
      U8 ua; ua.u[0]=pk2(a0.x,a0.y); ua.u[1]=pk2(a0.z,a0.w);
             ua.u[2]=pk2(a1.x,a1.y); ua.u[3]=pk2(a1.z,a1.w);
      zf[0][k1] = ua.v;
      U8 ub; ub.u[0]=pk2(c0.x,c0.y); ub.u[1]=pk2(c0.z,c0.w);
             ub.u[2]=pk2(c1.x,c1.y); ub.u[3]=pk2(c1.z,c1.w);
      zf[1][k1] = ub.v;
    }

    f32x4 acc2[2][4];
    #pragma unroll
    for (int t = 0; t < 2; ++t)
      #pragma unroll
      for (int m = 0; m < 4; ++m) acc2[t][m] = bias2[m];

    for (int ks = 0; ks < 8; ++ks) {
      // ---- layer 1 over hid m-tiles {2ks, 2ks+1} ----
      f32x4 acc1[2][2];
      #pragma unroll
      for (int mm = 0; mm < 2; ++mm) {
        int hb = 16 * (2*ks + mm) + 4*g;
        f32x4 bv = *reinterpret_cast<const f32x4*>(b1 + hb);  // L2-hot
        acc1[0][mm] = bv; acc1[1][mm] = bv;
      }
      #pragma unroll
      for (int mm = 0; mm < 2; ++mm) {
        uint32_t rowb = (uint32_t)(16*(2*ks+mm) + l15) * 128;
        #pragma unroll
        for (int k1 = 0; k1 < 2; ++k1) {
          bf16x8 a = *reinterpret_cast<const bf16x8*>(
              lds + rowb + (((uint32_t)(64*k1 + 16*g)) ^ swz));
          acc1[0][mm] = __builtin_amdgcn_mfma_f32_16x16x32_bf16(a, zf[0][k1], acc1[0][mm], 0,0,0);
          acc1[1][mm] = __builtin_amdgcn_mfma_f32_16x16x32_bf16(a, zf[1][k1], acc1[1][mm], 0,0,0);
        }
      }
      // ---- relu + bf16 pack: lane holds hid-local {16mm+4g+r} for zrow l15
      uint32_t c[2][4];
      #pragma unroll
      for (int t = 0; t < 2; ++t) {
        #pragma unroll
        for (int mm = 0; mm < 2; ++mm) {
          float h0 = fmaxf(acc1[t][mm][0], 0.f), h1 = fmaxf(acc1[t][mm][1], 0.f);
          float h2 = fmaxf(acc1[t][mm][2], 0.f), h3 = fmaxf(acc1[t][mm][3], 0.f);
          c[t][2*mm+0] = pk2(h0, h1);
          c[t][2*mm+1] = pk2(h2, h3);
        }
      }
      // ---- exchange -> layer2 B-frag: lane (group g) needs hid-local
      // {8g..8g+7}. Word p: source lane l15+16*((2g+(p>>1))&3), source word
      // 2*(g>>1)+(p&1). Fetch both mm-halves, select by consumer's g&2.
      U8 b2u[2];
      #pragma unroll
      for (int p = 0; p < 4; ++p) {
        int srcLane = l15 + 32*(g & 1) + 16*(p >> 1);   // == l15+16*((2g+(p>>1))&3)
        #pragma unroll
        for (int t = 0; t < 2; ++t) {
          uint32_t vlo = (uint32_t)__shfl((int)c[t][(p & 1)],     srcLane, 64);
          uint32_t vhi = (uint32_t)__shfl((int)c[t][2 + (p & 1)], srcLane, 64);
          b2u[t].u[p] = (g & 2) ? vhi : vlo;
        }
      }
      // ---- layer 2: O^T += W2T[:, 32ks..] @ Hchunk ----
      #pragma unroll
      for (int m = 0; m < 4; ++m) {
        uint32_t rowb = 32768u + (uint32_t)(16*m + l15) * 512;
        bf16x8 a = *reinterpret_cast<const bf16x8*>(
            lds + rowb + (((uint32_t)(64*ks + 16*g)) ^ swz));
        acc2[0][m] = __builtin_amdgcn_mfma_f32_16x16x32_bf16(a, b2u[0].v, acc2[0][m], 0,0,0);
        acc2[1][m] = __builtin_amdgcn_mfma_f32_16x16x32_bf16(a, b2u[1].v, acc2[1][m], 0,0,0);
      }
    }

    // ---- store: out col = 4 + mlp_out ----
    #pragma unroll
    for (int t = 0; t < 2; ++t) {
      const int row = (t == 0) ? r0 : r1;
      float* op = out + (size_t)row * 64;
      #pragma unroll
      for (int m = 0; m < 4; ++m) {
        int col = 4 + 16*m + 4*g;
        if (col < 64) {  // m==3 && g==3 is padding (outs 60..63)
          float4 v = make_float4(acc2[t][m][0], acc2[t][m][1],
                                 acc2[t][m][2], acc2[t][m][3]);
          *reinterpret_cast<float4*>(op + col) = v;
        }
      }
    }
  }
}

extern "C" void kernel_launch(void* const* d_in, const int* in_sizes, int n_in,
                              void* d_out, int out_size, void* d_ws, size_t ws_size,
                              hipStream_t stream) {
  const float* z  = (const float*)d_in[0];
  const float* W1 = (const float*)d_in[1];
  const float* b1 = (const float*)d_in[2];
  const float* W2 = (const float*)d_in[3];
  const float* b2 = (const float*)d_in[4];
  float* out = (float*)d_out;

  hipLaunchKernelGGL(veronese_quat, dim3(NROWS / 256), dim3(256), 0, stream,
                     z, out);
  hipLaunchKernelGGL(veronese_mlp, dim3(MLP_BLOCKS), dim3(256), 0, stream,
                     z, W1, b1, W2, b2, out);
}

// Round 4
// 152.618 us; speedup vs baseline: 3.6404x; 2.0694x over previous
//
#include <hip/hip_runtime.h>
#include <stdint.h>

#define NROWS 262144
#define INF   64
#define HIDN  256
#define OUTM  60
#define BLOCKS 512
#define ROWS_PER_ITER 256                      // per block per iter (4 waves x 64)
#define ITERS (NROWS / (BLOCKS * ROWS_PER_ITER))   // 2

typedef __attribute__((ext_vector_type(8))) short bf16x8;
typedef __attribute__((ext_vector_type(4))) float f32x4;

// 2x f32 -> packed bf16 (RNE), 1 instruction (T12 recipe)
__device__ __forceinline__ uint32_t pk2(float lo, float hi) {
  uint32_t r;
  asm("v_cvt_pk_bf16_f32 %0, %1, %2" : "=v"(r) : "v"(lo), "v"(hi));
  return r;
}

union U8 { uint32_t u[4]; bf16x8 v; uint4 q; };

// ---------------------------------------------------------------------------
// Fused kernel: quat (Jacobi, 1 lane/row) + 2-layer MLP (bf16 MFMA, transposed
// formulation). Wave handles 64 rows/iter: 4 MFMA row-tiles of 16, and each
// lane does the Jacobi for one of the 64 rows.
// LDS: W1T [256 hid][64 in] bf16 @0 (row=128B), W2T [64 outcol][256 hid] bf16
// @32768 (row=512B, rows 0-3 = zeros -> out cols 0-3 come from quat), both
// XOR-swizzled by ((row&7)<<4) on 16B units.
// ---------------------------------------------------------------------------
__global__ __launch_bounds__(256)
void veronese_fused(const float* __restrict__ z,  const float* __restrict__ W1,
                    const float* __restrict__ b1, const float* __restrict__ W2,
                    const float* __restrict__ b2, float* __restrict__ out) {
  __shared__ __align__(16) uint8_t lds[65536];
  const int tid = threadIdx.x;

  // ---- stage W1T: thread t owns hid row t ----
  {
    const int hid = tid;
    #pragma unroll
    for (int hc = 0; hc < 8; ++hc) {
      float f[8];
      #pragma unroll
      for (int j = 0; j < 8; ++j) f[j] = W1[(hc*8 + j) * HIDN + hid];
      U8 u;
      u.u[0] = pk2(f[0], f[1]); u.u[1] = pk2(f[2], f[3]);
      u.u[2] = pk2(f[4], f[5]); u.u[3] = pk2(f[6], f[7]);
      uint32_t off = (uint32_t)hid * 128 + (uint32_t)((hc * 16) ^ ((hid & 7) << 4));
      *reinterpret_cast<uint4*>(lds + off) = u.q;
    }
  }
  // ---- stage W2T: row o = out col; rows 0-3 zero (quat slot) ----
  {
    const int o  = tid & 63;
    const int qq = tid >> 6;
    #pragma unroll
    for (int hc = 0; hc < 8; ++hc) {
      const int hb = qq * 64 + hc * 8;
      float f[8];
      #pragma unroll
      for (int j = 0; j < 8; ++j)
        f[j] = (o >= 4) ? W2[(hb + j) * OUTM + (o - 4)] : 0.0f;
      U8 u;
      u.u[0] = pk2(f[0], f[1]); u.u[1] = pk2(f[2], f[3]);
      u.u[2] = pk2(f[4], f[5]); u.u[3] = pk2(f[6], f[7]);
      uint32_t off = 32768u + (uint32_t)o * 512 + (uint32_t)((hb * 2) ^ ((o & 7) << 4));
      *reinterpret_cast<uint4*>(lds + off) = u.q;
    }
  }
  __syncthreads();

  const int l   = tid & 63;
  const int w   = tid >> 6;
  const int g   = l >> 4;
  const int l15 = l & 15;
  const uint32_t swz = (uint32_t)((l & 7) << 4);
  // 4-slot exchange lane addresses (derivation in round notes; verified on
  // lane 37/g=2): slots 0,1 pull srcA; slots 2,3 pull srcB.
  const int srcA = l15 + 32*(g & 1) + 16*(g >> 1);
  const int srcB = l15 + 32*(g & 1) + 16*(1 - (g >> 1));
  const bool hiq = (g & 2) != 0;
  const bool amI16 = (l & 16) != 0;   // source-side word select: (srclane>>4)&1

  // bias2: out col = 16m+4g; col<4 is the quat slot (zero bias)
  f32x4 bias2[4];
  #pragma unroll
  for (int m = 0; m < 4; ++m) {
    int ob = 16*m + 4*g;
    if (ob >= 4) bias2[m] = *reinterpret_cast<const f32x4*>(b2 + ob - 4);
    else         bias2[m] = (f32x4){0.f, 0.f, 0.f, 0.f};
  }

  for (int it = 0; it < ITERS; ++it) {
    const int rowBase = (blockIdx.x * ITERS + it) * ROWS_PER_ITER + w * 64;

    // ---- z loads: quat row (this lane) + 4 MFMA B-frag tiles ----
    const float* zq = z + (size_t)(rowBase + l) * INF;
    float4 qv0 = reinterpret_cast<const float4*>(zq)[0];
    float4 qv1 = reinterpret_cast<const float4*>(zq)[1];
    float4 qv2 = reinterpret_cast<const float4*>(zq)[2];

    bf16x8 zf[4][2];
    #pragma unroll
    for (int t = 0; t < 4; ++t) {
      const float* zp = z + (size_t)(rowBase + 16*t + l15) * INF;
      #pragma unroll
      for (int k1 = 0; k1 < 2; ++k1) {
        float4 a0 = *reinterpret_cast<const float4*>(zp + k1*32 + 8*g);
        float4 a1 = *reinterpret_cast<const float4*>(zp + k1*32 + 8*g + 4);
        U8 u;
        u.u[0] = pk2(a0.x, a0.y); u.u[1] = pk2(a0.z, a0.w);
        u.u[2] = pk2(a1.x, a1.y); u.u[3] = pk2(a1.z, a1.w);
        zf[t][k1] = u.v;
      }
    }

    // ---- quat: branchless Jacobi, native transcendentals, 6 sweeps ----
    float q0, q1, q2, q3;
    {
      float zv[10] = {qv0.x,qv0.y,qv0.z,qv0.w, qv1.x,qv1.y,qv1.z,qv1.w,
                      qv2.x,qv2.y};
      float M[4][4];
      M[0][0]=zv[0]; M[0][1]=zv[1]; M[0][2]=zv[2]; M[0][3]=zv[3];
      M[1][1]=zv[4]; M[1][2]=zv[5]; M[1][3]=zv[6];
      M[2][2]=zv[7]; M[2][3]=zv[8]; M[3][3]=zv[9];
      M[1][0]=zv[1]; M[2][0]=zv[2]; M[3][0]=zv[3];
      M[2][1]=zv[5]; M[3][1]=zv[6]; M[3][2]=zv[8];
      float V[4][4] = {{1.f,0.f,0.f,0.f},{0.f,1.f,0.f,0.f},
                       {0.f,0.f,1.f,0.f},{0.f,0.f,0.f,1.f}};

#define JROT(p, q) do {                                                      \
      float apq = M[p][q];                                                   \
      float app = M[p][p], aqq = M[q][q];                                    \
      float tau = (aqq - app) * (0.5f * __builtin_amdgcn_rcpf(apq));         \
      float t_r = copysignf(1.0f, tau) *                                     \
          __builtin_amdgcn_rcpf(fabsf(tau) +                                 \
              __builtin_amdgcn_sqrtf(fmaf(tau, tau, 1.0f)));                 \
      float t   = (fabsf(apq) > 1e-25f) ? t_r : 0.0f;                        \
      float c   = __builtin_amdgcn_rsqf(fmaf(t, t, 1.0f));                   \
      float s   = t * c;                                                     \
      M[p][p] = fmaf(-t, apq, app);                                          \
      M[q][q] = fmaf( t, apq, aqq);                                          \
      M[p][q] = 0.0f; M[q][p] = 0.0f;                                        \
      _Pragma("unroll")                                                      \
      for (int r = 0; r < 4; ++r) {                                          \
        if (r != p && r != q) {                                              \
          float arp = M[r][p], arq = M[r][q];                                \
          float nrp = fmaf(-s, arq, c * arp);                                \
          float nrq = fmaf( s, arp, c * arq);                                \
          M[r][p] = nrp; M[p][r] = nrp;                                      \
          M[r][q] = nrq; M[q][r] = nrq;                                      \
        }                                                                    \
      }                                                                      \
      _Pragma("unroll")                                                      \
      for (int r = 0; r < 4; ++r) {                                          \
        float vrp = V[r][p], vrq = V[r][q];                                  \
        V[r][p] = fmaf(-s, vrq, c * vrp);                                    \
        V[r][q] = fmaf( s, vrp, c * vrq);                                    \
      }                                                                      \
    } while (0)

      #pragma unroll
      for (int sweep = 0; sweep < 6; ++sweep) {
        JROT(0, 1); JROT(0, 2); JROT(0, 3);
        JROT(1, 2); JROT(1, 3); JROT(2, 3);
      }
#undef JROT

      float bv = M[0][0];
      q0 = V[0][0]; q1 = V[1][0]; q2 = V[2][0]; q3 = V[3][0];
      #pragma unroll
      for (int j = 1; j < 4; ++j) {
        float dj = M[j][j];
        bool  b  = dj > bv;
        bv = b ? dj      : bv;
        q0 = b ? V[0][j] : q0;
        q1 = b ? V[1][j] : q1;
        q2 = b ? V[2][j] : q2;
        q3 = b ? V[3][j] : q3;
      }
      float sgn = (q0 < 0.0f) ? -1.0f : 1.0f;  // sign(0) -> +1
      q0 *= sgn; q1 *= sgn; q2 *= sgn; q3 *= sgn;
    }

    // ---- MLP ----
    f32x4 acc2[4][4];
    #pragma unroll
    for (int t = 0; t < 4; ++t)
      #pragma unroll
      for (int m = 0; m < 4; ++m) acc2[t][m] = bias2[m];

    for (int ks = 0; ks < 8; ++ks) {
      uint32_t c[4][4];
      // layer 1, two hid m-tiles (mm), A-frags shared across the 4 z-tiles
      #pragma unroll
      for (int mm = 0; mm < 2; ++mm) {
        const int hb = 16*(2*ks + mm) + 4*g;
        f32x4 bv = *reinterpret_cast<const f32x4*>(b1 + hb);   // L1-hot
        uint32_t rowb = (uint32_t)(16*(2*ks+mm) + l15) * 128;
        bf16x8 a0 = *reinterpret_cast<const bf16x8*>(
            lds + rowb + (((uint32_t)(16*g)) ^ swz));
        bf16x8 a1 = *reinterpret_cast<const bf16x8*>(
            lds + rowb + (((uint32_t)(64 + 16*g)) ^ swz));
        f32x4 acc1[4];
        #pragma unroll
        for (int t = 0; t < 4; ++t) {
          acc1[t] = __builtin_amdgcn_mfma_f32_16x16x32_bf16(a0, zf[t][0], bv, 0,0,0);
          acc1[t] = __builtin_amdgcn_mfma_f32_16x16x32_bf16(a1, zf[t][1], acc1[t], 0,0,0);
        }
        #pragma unroll
        for (int t = 0; t < 4; ++t) {
          float h0 = fmaxf(acc1[t][0], 0.f), h1 = fmaxf(acc1[t][1], 0.f);
          float h2 = fmaxf(acc1[t][2], 0.f), h3 = fmaxf(acc1[t][3], 0.f);
          c[t][2*mm+0] = pk2(h0, h1);
          c[t][2*mm+1] = pk2(h2, h3);
        }
      }
      // layer-2 A-frags (shared across tiles)
      bf16x8 a2[4];
      #pragma unroll
      for (int m = 0; m < 4; ++m) {
        uint32_t rowb = 32768u + (uint32_t)(16*m + l15) * 512;
        a2[m] = *reinterpret_cast<const bf16x8*>(
            lds + rowb + (((uint32_t)(64*ks + 16*g)) ^ swz));
      }
      // exchange + layer 2 per tile: 4 bpermutes (slot scheme), 8 cndmask
      #pragma unroll
      for (int t = 0; t < 4; ++t) {
        uint32_t v02a = amI16 ? c[t][2] : c[t][0];
        uint32_t v13a = amI16 ? c[t][3] : c[t][1];
        uint32_t v02b = amI16 ? c[t][0] : c[t][2];
        uint32_t v13b = amI16 ? c[t][1] : c[t][3];
        uint32_t s0 = (uint32_t)__shfl((int)v02a, srcA, 64);
        uint32_t s1 = (uint32_t)__shfl((int)v13a, srcA, 64);
        uint32_t s2 = (uint32_t)__shfl((int)v02b, srcB, 64);
        uint32_t s3 = (uint32_t)__shfl((int)v13b, srcB, 64);
        U8 bu;
        bu.u[0] = hiq ? s2 : s0;
        bu.u[1] = hiq ? s3 : s1;
        bu.u[2] = hiq ? s0 : s2;
        bu.u[3] = hiq ? s1 : s3;
        #pragma unroll
        for (int m = 0; m < 4; ++m)
          acc2[t][m] = __builtin_amdgcn_mfma_f32_16x16x32_bf16(a2[m], bu.v, acc2[t][m], 0,0,0);
      }
    }

    // ---- inject quat into out cols 0-3 (g==0 lanes, acc2[t][0]) ----
    #pragma unroll
    for (int t = 0; t < 4; ++t) {
      int src = 16*t + l15;
      float v0 = __shfl(q0, src, 64);
      float v1 = __shfl(q1, src, 64);
      float v2 = __shfl(q2, src, 64);
      float v3 = __shfl(q3, src, 64);
      if (g == 0) {
        acc2[t][0][0] = v0; acc2[t][0][1] = v1;
        acc2[t][0][2] = v2; acc2[t][0][3] = v3;
      }
    }

    // ---- store: 16 full float4s per row -> full 256B lines, no RMW ----
    #pragma unroll
    for (int t = 0; t < 4; ++t) {
      float* op = out + (size_t)(rowBase + 16*t + l15) * 64;
      #pragma unroll
      for (int m = 0; m < 4; ++m) {
        float4 v = make_float4(acc2[t][m][0], acc2[t][m][1],
                               acc2[t][m][2], acc2[t][m][3]);
        *reinterpret_cast<float4*>(op + 16*m + 4*g) = v;
      }
    }
  }
}

extern "C" void kernel_launch(void* const* d_in, const int* in_sizes, int n_in,
                              void* d_out, int out_size, void* d_ws, size_t ws_size,
                              hipStream_t stream) {
  const float* z  = (const float*)d_in[0];
  const float* W1 = (const float*)d_in[1];
  const float* b1 = (const float*)d_in[2];
  const float* W2 = (const float*)d_in[3];
  const float* b2 = (const float*)d_in[4];
  float* out = (float*)d_out;

  hipLaunchKernelGGL(veronese_fused, dim3(BLOCKS), dim3(256), 0, stream,
                     z, W1, b1, W2, b2, out);
}